// Round 5
// baseline (99.908 us; speedup 1.0000x reference)
//
#include <hip/hip_runtime.h>
#include <math.h>

#define MM 32
#define NN 8192
#define DD 64
#define KK 16

// ---------------------------------------------------------------------------
// Kernel 1: per-component precompute via Woodbury.
//   Mk = I + Lambda^T P^{-1} Lambda  (16x16), P = diag(Psi + 1e-6)
//   Minv[m] = Mk^{-1} (== term1);  const[m] = log pi - 0.5*(D log2pi + logdet)
// ---------------------------------------------------------------------------
__global__ __launch_bounds__(256) void mfa_pre(
    const float* __restrict__ pi, const float* __restrict__ Lambda,
    const float* __restrict__ Psi, float* __restrict__ Minv_out,
    float* __restrict__ const_out) {
  const int m = blockIdx.x;
  const int tid = threadIdx.x;
  __shared__ float lam[DD * KK];
  __shared__ float pinv[DD];
  __shared__ float Mmat[KK * KK];
  __shared__ float Lmat[KK * KK];
  __shared__ float vbuf[KK];

  for (int idx = tid; idx < DD * KK; idx += 256)
    lam[idx] = Lambda[(size_t)m * DD * KK + idx];
  if (tid < DD) pinv[tid] = 1.0f / (Psi[tid] + 1e-6f);
  __syncthreads();

  {
    const int k = tid >> 4, j = tid & 15;
    float a = 0.0f;
    for (int d = 0; d < DD; ++d)
      a += lam[d * KK + k] * lam[d * KK + j] * pinv[d];
    Mmat[tid] = a + (k == j ? 1.0f : 0.0f);
  }
  __syncthreads();

  // Cooperative right-looking Cholesky: thread r owns row r in registers.
  float lr[KK];
  if (tid < KK) {
#pragma unroll
    for (int j = 0; j < KK; ++j) lr[j] = Mmat[tid * KK + j];
  }
#pragma unroll
  for (int c = 0; c < KK; ++c) {
    if (tid < KK) vbuf[tid] = lr[c];
    __syncthreads();
    if (tid < KK) {
      const float vc = vbuf[c];
      const float dc = sqrtf(vc);
      const float lrc = lr[c] / dc;
      if (tid >= c) Lmat[tid * KK + c] = lrc;
      const float s = lr[c] / vc;
#pragma unroll
      for (int j = 0; j < KK; ++j)
        if (j > c) lr[j] -= s * vbuf[j];
    }
    __syncthreads();
  }

  if (tid < KK) {
    const int col = tid;
    float y[KK], z[KK];
#pragma unroll
    for (int i = 0; i < KK; ++i) {
      float s = (i == col) ? 1.0f : 0.0f;
#pragma unroll
      for (int p = 0; p < KK; ++p)
        if (p < i) s -= Lmat[i * KK + p] * y[p];
      y[i] = s / Lmat[i * KK + i];
    }
#pragma unroll
    for (int i = KK - 1; i >= 0; --i) {
      float s = y[i];
#pragma unroll
      for (int p = 0; p < KK; ++p)
        if (p > i) s -= Lmat[p * KK + i] * z[p];
      z[i] = s / Lmat[i * KK + i];
    }
#pragma unroll
    for (int i = 0; i < KK; ++i)
      Minv_out[(size_t)m * KK * KK + i * KK + col] = z[i];
  }

  if (tid == 0) {
    float logdetM = 0.0f;
#pragma unroll
    for (int c = 0; c < KK; ++c) logdetM += logf(Lmat[c * KK + c]);
    logdetM *= 2.0f;
    float logdetP = 0.0f;
    for (int d = 0; d < DD; ++d) logdetP -= logf(pinv[d]);
    const float LOG2PI = 1.8378770664093453f;
    const_out[m] =
        logf(pi[m] + 1e-10f) - 0.5f * (DD * LOG2PI + logdetP + logdetM);
  }
}

// ---------------------------------------------------------------------------
// Kernel 2: fused main pass, 2-chunk software pipeline per block.
// grid = 512 blocks (2/CU -> 8 waves/CU, 2 waves/SIMD). Block b owns
// component m = b>>4 and two 256-sample tiles: ntile = (b&15) + it*16,
// it in {0,1}. Shared params (Wl, mu, Minv, const) staged ONCE before the
// loop (the only __syncthreads). Inside the loop everything is wave-local
// (disjoint LDS slices, in-order DS pipe): compute e_z -> stage in LDS ->
// stream e_z + e_zz stores with no block barrier. While one wave stalls
// issuing chunk-0 stores against queue backpressure, its SIMD-mate
// computes chunk 1 -> store drain runs continuously.
// ---------------------------------------------------------------------------
__global__ __launch_bounds__(256) void mfa_main(
    const float* __restrict__ X, const float* __restrict__ mu,
    const float* __restrict__ Lambda, const float* __restrict__ Psi,
    const float* __restrict__ Minv, const float* __restrict__ cconst,
    float* __restrict__ out) {
  const int b = blockIdx.x;
  const int m = b >> 4;
  const int tid = threadIdx.x;
  const int w = tid >> 6, l = tid & 63;

  __shared__ float Wl[DD * KK];      // P^{-1} Lambda_m  (4KB)
  __shared__ float pinv[DD];
  __shared__ float mul[DD];
  __shared__ float minv_l[KK * KK];  // 1KB
  __shared__ float ez_l[256 * KK];   // 16KB, wave w owns [w*64*KK, +4KB)

  if (tid < DD) {
    pinv[tid] = 1.0f / (Psi[tid] + 1e-6f);
    mul[tid] = mu[m * DD + tid];
  }
  minv_l[tid] = Minv[(size_t)m * KK * KK + tid];
  __syncthreads();
  for (int idx = tid; idx < DD * KK; idx += 256)
    Wl[idx] = Lambda[(size_t)m * DD * KK + idx] * pinv[idx >> 4];
  __syncthreads();  // only block-wide barrier: shared params ready

  const float cst = cconst[m];
  const int i_ = l >> 2, jq = l & 3;
  const float4 mreg = reinterpret_cast<const float4*>(minv_l)[l];
  const float4* ezl4 =
      reinterpret_cast<const float4*>(ez_l + (size_t)w * 64 * KK);

  for (int it = 0; it < 2; ++it) {
    const int n0 = ((b & 15) + it * 16) * 256;
    const int n = n0 + tid;

    float u[KK];
#pragma unroll
    for (int k = 0; k < KK; ++k) u[k] = 0.0f;
    float q = 0.0f;
    const float4* X4 = reinterpret_cast<const float4*>(X + (size_t)n * DD);
#pragma unroll
    for (int d4 = 0; d4 < DD / 4; ++d4) {
      const float4 xv = X4[d4];
      const float xs[4] = {xv.x, xv.y, xv.z, xv.w};
#pragma unroll
      for (int s = 0; s < 4; ++s) {
        const int d = d4 * 4 + s;
        const float df = xs[s] - mul[d];
        q += df * df * pinv[d];
#pragma unroll
        for (int k = 0; k < KK; ++k) u[k] += Wl[d * KK + k] * df;
      }
    }

    float ez[KK];
    float udot = 0.0f;
#pragma unroll
    for (int i = 0; i < KK; ++i) {
      float s = 0.0f;
#pragma unroll
      for (int j = 0; j < KK; ++j) s += minv_l[i * KK + j] * u[j];
      ez[i] = s;
      udot += u[i] * s;
    }
    const float maha = q - udot;
    out[(size_t)n * MM + m] = cst - 0.5f * maha;  // logit; softmax later

#pragma unroll
    for (int k = 0; k < KK; ++k) ez_l[tid * KK + k] = ez[k];

    // ---- wave-local phase switch (no __syncthreads) ----
    __builtin_amdgcn_wave_barrier();
    asm volatile("s_waitcnt lgkmcnt(0)" ::: "memory");

    const int sbase = n0 + w * 64;  // first sample owned by this wave

    // e_z out: wave's 64 samples * 16 floats = 256 float4, coalesced
    float4* ezo = reinterpret_cast<float4*>(
        out + (size_t)NN * MM + ((size_t)m * NN + sbase) * KK);
#pragma unroll
    for (int i = 0; i < 4; ++i) ezo[i * 64 + l] = ezl4[i * 64 + l];

    // e_zz out: per iteration the wave writes one sample's full 16x16 tile
    // (64 lanes x float4 = 1KB, coalesced). lane l: row l>>2, col-quad l&3.
    float4* zzo = reinterpret_cast<float4*>(out + (size_t)NN * MM +
                                            (size_t)MM * NN * KK) +
                  ((size_t)m * NN + sbase) * 64;
#pragma unroll 4
    for (int nl = 0; nl < 64; ++nl) {
      const float ezi = ez_l[((size_t)w * 64 + nl) * KK + i_];
      const float4 ezj = ezl4[nl * 4 + jq];
      float4 o;
      o.x = mreg.x + ezi * ezj.x;
      o.y = mreg.y + ezi * ezj.y;
      o.z = mreg.z + ezi * ezj.z;
      o.w = mreg.w + ezi * ezj.w;
      zzo[nl * 64 + l] = o;
    }
    // no fence needed before next chunk: DS ops are in-order per wave and
    // next chunk's ds_writes hit the same wave-private slice.
  }
}

// ---------------------------------------------------------------------------
// Kernel 3: in-place softmax over the M=32 logits per sample.
// ---------------------------------------------------------------------------
__global__ __launch_bounds__(256) void mfa_softmax(float* __restrict__ out) {
  const int n = blockIdx.x * 256 + threadIdx.x;
  float4* p = reinterpret_cast<float4*>(out) + (size_t)n * (MM / 4);
  float v[MM];
#pragma unroll
  for (int i = 0; i < MM / 4; ++i) {
    const float4 t = p[i];
    v[4 * i] = t.x; v[4 * i + 1] = t.y; v[4 * i + 2] = t.z; v[4 * i + 3] = t.w;
  }
  float mx = -3.4e38f;
#pragma unroll
  for (int i = 0; i < MM; ++i) mx = fmaxf(mx, v[i]);
  float s = 0.0f;
#pragma unroll
  for (int i = 0; i < MM; ++i) { v[i] = expf(v[i] - mx); s += v[i]; }
  const float inv = 1.0f / s;
#pragma unroll
  for (int i = 0; i < MM / 4; ++i) {
    float4 t;
    t.x = v[4 * i] * inv; t.y = v[4 * i + 1] * inv;
    t.z = v[4 * i + 2] * inv; t.w = v[4 * i + 3] * inv;
    p[i] = t;
  }
}

extern "C" void kernel_launch(void* const* d_in, const int* in_sizes, int n_in,
                              void* d_out, int out_size, void* d_ws,
                              size_t ws_size, hipStream_t stream) {
  const float* X = (const float*)d_in[0];
  const float* pi = (const float*)d_in[1];
  const float* mu = (const float*)d_in[2];
  const float* Lambda = (const float*)d_in[3];
  const float* Psi = (const float*)d_in[4];
  float* out = (float*)d_out;

  float* Minv = (float*)d_ws;           // 32*256 floats = 32KB
  float* cconst = Minv + MM * KK * KK;  // 32 floats

  mfa_pre<<<MM, 256, 0, stream>>>(pi, Lambda, Psi, Minv, cconst);
  mfa_main<<<512, 256, 0, stream>>>(X, mu, Lambda, Psi, Minv, cconst, out);
  mfa_softmax<<<NN / 256, 256, 0, stream>>>(out);
}

// Round 6
// 77.840 us; speedup vs baseline: 1.2835x; 1.2835x over previous
//
#include <hip/hip_runtime.h>
#include <math.h>

#define MM 32
#define NN 8192
#define DD 64
#define KK 16

// ---------------------------------------------------------------------------
// Kernel 1: per-component precompute via Woodbury.
//   Mk = I + Lambda^T P^{-1} Lambda  (16x16), P = diag(Psi + 1e-6)
//   Minv[m] = Mk^{-1} (== term1);  const[m] = log pi - 0.5*(D log2pi + logdet)
// Also exports pinv[64] and Wl[m] = P^{-1} Lambda_m (for the main kernel's
// uniform scalar-path loads).
// ---------------------------------------------------------------------------
__global__ __launch_bounds__(256) void mfa_pre(
    const float* __restrict__ pi, const float* __restrict__ Lambda,
    const float* __restrict__ Psi, float* __restrict__ Minv_out,
    float* __restrict__ const_out, float* __restrict__ pinv_out,
    float* __restrict__ Wl_out) {
  const int m = blockIdx.x;
  const int tid = threadIdx.x;
  __shared__ float lam[DD * KK];
  __shared__ float pinv[DD];
  __shared__ float Mmat[KK * KK];
  __shared__ float Lmat[KK * KK];
  __shared__ float vbuf[KK];

  for (int idx = tid; idx < DD * KK; idx += 256)
    lam[idx] = Lambda[(size_t)m * DD * KK + idx];
  if (tid < DD) pinv[tid] = 1.0f / (Psi[tid] + 1e-6f);
  __syncthreads();

  // export Wl and (racy-but-identical across blocks) pinv
  for (int idx = tid; idx < DD * KK; idx += 256)
    Wl_out[(size_t)m * DD * KK + idx] = lam[idx] * pinv[idx >> 4];
  if (tid < DD) pinv_out[tid] = pinv[tid];

  {
    const int k = tid >> 4, j = tid & 15;
    float a = 0.0f;
    for (int d = 0; d < DD; ++d)
      a += lam[d * KK + k] * lam[d * KK + j] * pinv[d];
    Mmat[tid] = a + (k == j ? 1.0f : 0.0f);
  }
  __syncthreads();

  // Cooperative right-looking Cholesky: thread r owns row r in registers.
  float lr[KK];
  if (tid < KK) {
#pragma unroll
    for (int j = 0; j < KK; ++j) lr[j] = Mmat[tid * KK + j];
  }
#pragma unroll
  for (int c = 0; c < KK; ++c) {
    if (tid < KK) vbuf[tid] = lr[c];
    __syncthreads();
    if (tid < KK) {
      const float vc = vbuf[c];
      const float dc = sqrtf(vc);
      const float lrc = lr[c] / dc;
      if (tid >= c) Lmat[tid * KK + c] = lrc;
      const float s = lr[c] / vc;
#pragma unroll
      for (int j = 0; j < KK; ++j)
        if (j > c) lr[j] -= s * vbuf[j];
    }
    __syncthreads();
  }

  if (tid < KK) {
    const int col = tid;
    float y[KK], z[KK];
#pragma unroll
    for (int i = 0; i < KK; ++i) {
      float s = (i == col) ? 1.0f : 0.0f;
#pragma unroll
      for (int p = 0; p < KK; ++p)
        if (p < i) s -= Lmat[i * KK + p] * y[p];
      y[i] = s / Lmat[i * KK + i];
    }
#pragma unroll
    for (int i = KK - 1; i >= 0; --i) {
      float s = y[i];
#pragma unroll
      for (int p = 0; p < KK; ++p)
        if (p > i) s -= Lmat[p * KK + i] * z[p];
      z[i] = s / Lmat[i * KK + i];
    }
#pragma unroll
    for (int i = 0; i < KK; ++i)
      Minv_out[(size_t)m * KK * KK + i * KK + col] = z[i];
  }

  if (tid == 0) {
    float logdetM = 0.0f;
#pragma unroll
    for (int c = 0; c < KK; ++c) logdetM += logf(Lmat[c * KK + c]);
    logdetM *= 2.0f;
    float logdetP = 0.0f;
    for (int d = 0; d < DD; ++d) logdetP -= logf(pinv[d]);
    const float LOG2PI = 1.8378770664093453f;
    const_out[m] =
        logf(pi[m] + 1e-10f) - 0.5f * (DD * LOG2PI + logdetP + logdetM);
  }
}

// ---------------------------------------------------------------------------
// Kernel 2: fused main pass, barrier-free. grid = (N/256, M), 16 waves/CU.
// All per-component broadcast data (Wl, mu, pinv, Minv) is read via
// wave-UNIFORM global loads -> scalar-cache / L1 path, keeping the LDS pipe
// free for the per-wave ez staging only. Each wave owns 64 samples
// end-to-end: compute u/e_z/logit -> stage e_z in its private 4KB LDS slice
// -> stream e_z + e_zz stores. No __syncthreads anywhere.
// ---------------------------------------------------------------------------
__global__ __launch_bounds__(256) void mfa_main(
    const float* __restrict__ X, const float* __restrict__ mu,
    const float* __restrict__ Minv, const float* __restrict__ cconst,
    const float* __restrict__ pinvG, const float* __restrict__ WlG,
    float* __restrict__ out) {
  const int m = blockIdx.y;
  const int n0 = blockIdx.x * 256;
  const int tid = threadIdx.x;
  const int w = tid >> 6, l = tid & 63;

  __shared__ float ez_l[256 * KK];  // 16KB, wave w owns [w*64*KK, +4KB)

  const float* Wlm = WlG + (size_t)m * DD * KK;  // uniform rows
  const float* mum = mu + m * DD;
  const float* Mi = Minv + (size_t)m * KK * KK;
  const float cst = cconst[m];

  const int n = n0 + tid;

  float u[KK];
#pragma unroll
  for (int k = 0; k < KK; ++k) u[k] = 0.0f;
  float q = 0.0f;
  const float4* X4 = reinterpret_cast<const float4*>(X + (size_t)n * DD);
#pragma unroll
  for (int d4 = 0; d4 < DD / 4; ++d4) {
    const float4 xv = X4[d4];                                     // per-lane
    const float4 muv = *reinterpret_cast<const float4*>(mum + d4 * 4);  // unif
    const float4 piv = *reinterpret_cast<const float4*>(pinvG + d4 * 4);
    const float xs[4] = {xv.x, xv.y, xv.z, xv.w};
    const float ms[4] = {muv.x, muv.y, muv.z, muv.w};
    const float ps[4] = {piv.x, piv.y, piv.z, piv.w};
#pragma unroll
    for (int s = 0; s < 4; ++s) {
      const int d = d4 * 4 + s;
      const float df = xs[s] - ms[s];
      q += df * df * ps[s];
      const float4* wr = reinterpret_cast<const float4*>(Wlm + d * KK);
#pragma unroll
      for (int k4 = 0; k4 < 4; ++k4) {
        const float4 wv = wr[k4];  // uniform
        u[k4 * 4 + 0] += wv.x * df;
        u[k4 * 4 + 1] += wv.y * df;
        u[k4 * 4 + 2] += wv.z * df;
        u[k4 * 4 + 3] += wv.w * df;
      }
    }
  }

  float ez[KK];
  float udot = 0.0f;
#pragma unroll
  for (int i = 0; i < KK; ++i) {
    const float4* mr = reinterpret_cast<const float4*>(Mi + i * KK);
    float s = 0.0f;
#pragma unroll
    for (int j4 = 0; j4 < 4; ++j4) {
      const float4 mv = mr[j4];  // uniform
      s += mv.x * u[j4 * 4 + 0] + mv.y * u[j4 * 4 + 1] +
           mv.z * u[j4 * 4 + 2] + mv.w * u[j4 * 4 + 3];
    }
    ez[i] = s;
    udot += u[i] * s;
  }
  const float maha = q - udot;
  out[(size_t)n * MM + m] = cst - 0.5f * maha;  // logit; softmax later

#pragma unroll
  for (int k = 0; k < KK; ++k) ez_l[tid * KK + k] = ez[k];

  // ---- wave-local phase switch (no __syncthreads) ----
  __builtin_amdgcn_wave_barrier();
  asm volatile("s_waitcnt lgkmcnt(0)" ::: "memory");

  const int sbase = n0 + w * 64;  // first sample owned by this wave
  const float4* ezl4 =
      reinterpret_cast<const float4*>(ez_l + (size_t)w * 64 * KK);

  // e_z out: wave's 64 samples * 16 floats = 256 float4, coalesced
  float4* ezo = reinterpret_cast<float4*>(
      out + (size_t)NN * MM + ((size_t)m * NN + sbase) * KK);
#pragma unroll
  for (int it = 0; it < 4; ++it) ezo[it * 64 + l] = ezl4[it * 64 + l];

  // e_zz out: per iteration the wave writes one sample's full 16x16 tile
  // (64 lanes x float4 = 1KB, coalesced). lane l: row i_=l>>2, col-quad l&3.
  const int i_ = l >> 2, jq = l & 3;
  const float4 mreg = reinterpret_cast<const float4*>(Mi)[l];  // per-lane
  float4* zzo = reinterpret_cast<float4*>(out + (size_t)NN * MM +
                                          (size_t)MM * NN * KK) +
                ((size_t)m * NN + sbase) * 64;
#pragma unroll 4
  for (int nl = 0; nl < 64; ++nl) {
    const float ezi = ez_l[((size_t)w * 64 + nl) * KK + i_];
    const float4 ezj = ezl4[nl * 4 + jq];
    float4 o;
    o.x = mreg.x + ezi * ezj.x;
    o.y = mreg.y + ezi * ezj.y;
    o.z = mreg.z + ezi * ezj.z;
    o.w = mreg.w + ezi * ezj.w;
    zzo[nl * 64 + l] = o;
  }
}

// ---------------------------------------------------------------------------
// Kernel 3: in-place softmax over the M=32 logits per sample.
// ---------------------------------------------------------------------------
__global__ __launch_bounds__(256) void mfa_softmax(float* __restrict__ out) {
  const int n = blockIdx.x * 256 + threadIdx.x;
  float4* p = reinterpret_cast<float4*>(out) + (size_t)n * (MM / 4);
  float v[MM];
#pragma unroll
  for (int i = 0; i < MM / 4; ++i) {
    const float4 t = p[i];
    v[4 * i] = t.x; v[4 * i + 1] = t.y; v[4 * i + 2] = t.z; v[4 * i + 3] = t.w;
  }
  float mx = -3.4e38f;
#pragma unroll
  for (int i = 0; i < MM; ++i) mx = fmaxf(mx, v[i]);
  float s = 0.0f;
#pragma unroll
  for (int i = 0; i < MM; ++i) { v[i] = expf(v[i] - mx); s += v[i]; }
  const float inv = 1.0f / s;
#pragma unroll
  for (int i = 0; i < MM / 4; ++i) {
    float4 t;
    t.x = v[4 * i] * inv; t.y = v[4 * i + 1] * inv;
    t.z = v[4 * i + 2] * inv; t.w = v[4 * i + 3] * inv;
    p[i] = t;
  }
}

extern "C" void kernel_launch(void* const* d_in, const int* in_sizes, int n_in,
                              void* d_out, int out_size, void* d_ws,
                              size_t ws_size, hipStream_t stream) {
  const float* X = (const float*)d_in[0];
  const float* pi = (const float*)d_in[1];
  const float* mu = (const float*)d_in[2];
  const float* Lambda = (const float*)d_in[3];
  const float* Psi = (const float*)d_in[4];
  float* out = (float*)d_out;

  float* Minv = (float*)d_ws;             // 32*256 floats
  float* cconst = Minv + MM * KK * KK;    // 32
  float* pinvG = cconst + MM;             // 64
  float* WlG = pinvG + DD;                // 32*1024

  mfa_pre<<<MM, 256, 0, stream>>>(pi, Lambda, Psi, Minv, cconst, pinvG, WlG);
  mfa_main<<<dim3(NN / 256, MM), 256, 0, stream>>>(X, mu, Minv, cconst, pinvG,
                                                   WlG, out);
  mfa_softmax<<<NN / 256, 256, 0, stream>>>(out);
}